// Round 12
// baseline (846.097 us; speedup 1.0000x reference)
//
#include <hip/hip_runtime.h>
#include <math.h>

typedef _Float16 hfrag  __attribute__((ext_vector_type(8)));  // 8 f16 = 4 VGPR (MFMA A/B)
typedef _Float16 hpack  __attribute__((ext_vector_type(4)));  // 4 f16 = 8B packed store
typedef float    accf   __attribute__((ext_vector_type(16))); // MFMA C/D

constexpr float cTB = 6.0f;
constexpr float cMB = 0.001f;
constexpr float cMD = 0.001f;

constexpr int SH = 136;   // act buffer stride (halves)
constexpr int SE = 72;    // emb buffer stride (halves)
constexpr int SP = 100;   // dedicated p buffer stride (halves)

__device__ __forceinline__ float eluf(float x)  { return x > 0.f ? x : __expf(x) - 1.f; }
__device__ __forceinline__ float sigmf(float x) { return 1.f / (1.f + __expf(-x)); }
__device__ __forceinline__ float softplusf_(float x) { return x > 20.f ? x : log1pf(__expf(x)); }

// ---------------- weight prep: fp32 [n][K][F] -> fragment-ordered f16 ----------------
// dst layout [n][fs][cstep][lane][8]: lane l of fragment (fs,cstep) holds
//   W[k = cstep*16 + (l>>5)*8 + j][f = fs*32 + (l&31)],  j = 0..7
__global__ void prep_frag(const float* __restrict__ src, _Float16* __restrict__ dst,
                          int K, int F, int Fpad, int total) {
  int idx = blockIdx.x * 256 + threadIdx.x;
  if (idx >= total) return;
  const int j    = idx & 7;
  const int lane = (idx >> 3) & 63;
  const int rest = idx >> 9;              // [n][fs][cstep]
  const int csteps = K >> 4;
  const int cstep  = rest % csteps;
  const int rest2  = rest / csteps;
  const int fslices = Fpad >> 5;
  const int fs = rest2 % fslices;
  const int n  = rest2 / fslices;
  const int f  = fs * 32 + (lane & 31);
  const int k  = cstep * 16 + ((lane >> 5) << 3) + j;
  float v = (f < F) ? src[((size_t)n * K + k) * F + f] : 0.f;
  dst[idx] = (_Float16)v;
}

// ---------------- bias prep: cbias = init_b + ctx_b; obias = out_b padded to 96 ----
__global__ void prep_bias(const float* __restrict__ gib, const float* __restrict__ gcb,
                          const float* __restrict__ gob, float* __restrict__ cb,
                          float* __restrict__ ob) {
  int i = blockIdx.x * 256 + threadIdx.x;
  if (i < 768) cb[i] = gib[i] + gcb[i];            // 6 layers x 128
  if (i < 576) {                                   // 6 layers x 96 (pad col 95)
    int l = i / 96, f = i % 96;
    ob[i] = (f < 95) ? gob[l * 95 + f] : 0.f;
  }
}

// GEMM, B from LDS: D[f][m] += W^T[f][k] * Act^T[k][m].  A-frag contiguous burst,
// B-frag col = m (LDS [m][k]).  Two n-tiles (m 0-31, 32-63).
// K-loop chunked at 2 c-steps (sched_barrier between) so the scheduler can't
// hoist more than ~24 regs of operand fragments — keeps t2-phase peak liveness
// under the 128-reg cap (R8: 8-step hoist = 63 MB spill; R11 4-step = 33 MB).
#define GEMM2(WBASE, BPTR, BSTRIDE, KDIM, A0, A1)                              \
  _Pragma("unroll")                                                            \
  for (int cc = 0; cc < (KDIM); cc += 32) {                                    \
    _Pragma("unroll")                                                          \
    for (int c = cc; c < cc + 32; c += 16) {                                   \
      hfrag av = *(const hfrag*)((WBASE) + (c << 5) + lane8);                  \
      hfrag b0 = *(const hfrag*)((BPTR) + col * (BSTRIDE) + c + q8);           \
      hfrag b1 = *(const hfrag*)((BPTR) + (32 + col) * (BSTRIDE) + c + q8);    \
      A0 = __builtin_amdgcn_mfma_f32_32x32x16_f16(av, b0, A0, 0, 0, 0);        \
      A1 = __builtin_amdgcn_mfma_f32_32x32x16_f16(av, b1, A1, 0, 0, 0);        \
    }                                                                          \
    __builtin_amdgcn_sched_barrier(0);                                         \
  }

__global__ __launch_bounds__(256, 4) void nsf_mfma(
    const float* __restrict__ gy,   const float* __restrict__ gctx,
    const float* __restrict__ eW1,  const float* __restrict__ eb1,
    const float* __restrict__ eb2,  const float* __restrict__ eb3,
    const float* __restrict__ cbias, const float* __restrict__ bb1,
    const float* __restrict__ bb2,  const float* __restrict__ bbc,
    const float* __restrict__ obias,
    const _Float16* __restrict__ wE2T, const _Float16* __restrict__ wE3T,
    const _Float16* __restrict__ wCtxT, const _Float16* __restrict__ wW1T,
    const _Float16* __restrict__ wW2T,  const _Float16* __restrict__ wWcT,
    const _Float16* __restrict__ wOutT, float* __restrict__ gout)
{
  __shared__ _Float16 sA[64 * SH];   // single in-place act buffer
  __shared__ _Float16 sE[64 * SE];   // embedding [m][k]
  __shared__ _Float16 sP[64 * SP];   // dedicated p buffer (spline input)

  const int tid  = threadIdx.x;
  const int wid  = tid >> 6;      // wave 0..3 -> f-slice
  const int lane = tid & 63;
  const int col  = lane & 31;     // MFMA col (= m_local)
  const int q    = lane >> 5;     // k-half selector
  const int q8   = q * 8;
  const int q4   = q * 4;
  const int f0   = wid * 32;
  const int m0   = blockIdx.x * 64;
  const int lane8 = lane * 8;     // fragment-ordered weight lane offset (halves)

  // ---------------- embedding ----------------
  {  // stage 1: fp32, 4 e-groups x 64 m -> sE
    const int m  = tid & 63;
    const int eg = tid >> 6;
    const float2 c2 = *(const float2*)&gctx[(size_t)(m0 + m) * 2];
    #pragma unroll
    for (int j = 0; j < 16; ++j) {
      const int e = eg * 16 + j;
      sE[m * SE + e] = (_Float16)eluf(c2.x * eW1[e] + c2.y * eW1[64 + e] + eb1[e]);
    }
  }
  __syncthreads();
  {  // stage 2: MFMA, each wave one (ft, nt) tile: sE -> sA (stride SE)
    const int ft = wid & 1, nt = wid >> 1;
    accf a = {};
    const _Float16* wr = wE2T + ft * 2048;     // [fs][cs=4][64][8]
    #pragma unroll
    for (int c = 0; c < 64; c += 16) {
      hfrag av = *(const hfrag*)(wr + (c << 5) + lane8);
      hfrag bv = *(const hfrag*)(&sE[(nt * 32 + col) * SE + c + q8]);
      a = __builtin_amdgcn_mfma_f32_32x32x16_f16(av, bv, a, 0, 0, 0);
    }
    const int mrow = nt * 32 + col;
    __syncthreads();   // sE reads done everywhere before stage-3 overwrites
    #pragma unroll
    for (int g = 0; g < 4; ++g) {
      const int e = 32 * ft + 8 * g + q4;
      const float4 b = *(const float4*)&eb2[e];
      hpack pk;
      #pragma unroll
      for (int r = 0; r < 4; ++r) pk[r] = (_Float16)eluf(a[4 * g + r] + (&b.x)[r]);
      *(hpack*)&sA[mrow * SE + e] = pk;
    }
  }
  __syncthreads();
  {  // stage 3: MFMA: sA -> sE (final embedding)
    const int ft = wid & 1, nt = wid >> 1;
    accf a = {};
    const _Float16* wr = wE3T + ft * 2048;
    #pragma unroll
    for (int c = 0; c < 64; c += 16) {
      hfrag av = *(const hfrag*)(wr + (c << 5) + lane8);
      hfrag bv = *(const hfrag*)(&sA[(nt * 32 + col) * SE + c + q8]);
      a = __builtin_amdgcn_mfma_f32_32x32x16_f16(av, bv, a, 0, 0, 0);
    }
    const int mrow = nt * 32 + col;
    #pragma unroll
    for (int g = 0; g < 4; ++g) {
      const int e = 32 * ft + 8 * g + q4;
      const float4 b = *(const float4*)&eb3[e];
      hpack pk;
      #pragma unroll
      for (int r = 0; r < 4; ++r) pk[r] = (_Float16)eluf(a[4 * g + r] + (&b.x)[r]);
      *(hpack*)&sE[mrow * SE + e] = pk;
    }
  }
  __syncthreads();

  // ---------------- flow layers ----------------
  float z = 0.f, lad = 0.f;
  if (tid < 64) z = gy[m0 + tid];

  accf h0, h1;   // raw h (fp32) for this wave's f-slice, n-tiles 0/1

  #pragma unroll 1
  for (int l = 0; l < 6; ++l) {
    // ---- ctx GEMM (reads sE only): waves 1-3 run ahead here while wave 0
    //      finishes the previous layer's spline (reads sP — disjoint buffer).
    {
      accf a0 = {}, a1 = {};
      const _Float16* wr = wCtxT + (size_t)l * 8192 + wid * 2048;  // 4 fs x 4 cs x 512
      GEMM2(wr, sE, SE, 64, a0, a1)
      // ---- ctx epilogue: h = acc + (init_b+ctx_b); write elu(h) -> sA ----
      #pragma unroll
      for (int nt = 0; nt < 2; ++nt) {
        accf& A = nt ? a1 : a0;
        accf& H = nt ? h1 : h0;
        const int mrow = nt * 32 + col;
        #pragma unroll
        for (int g = 0; g < 4; ++g) {
          const int f = f0 + 8 * g + q4;
          const float4 bi = *(const float4*)&cbias[l * 128 + f];
          hpack pk;
          #pragma unroll
          for (int r = 0; r < 4; ++r) {
            float hv = A[4 * g + r] + (&bi.x)[r];
            H[4 * g + r] = hv;
            pk[r] = (_Float16)eluf(hv);
          }
          *(hpack*)&sA[mrow * SH + f] = pk;
        }
      }
    }
    __syncthreads();   // (B) elu(h) visible

    // ---- residual blocks (in-place on sA) ----
    #pragma unroll 1
    for (int jb = 0; jb < 2; ++jb) {
      const int wi = l * 2 + jb;
      {  // t1 = elu(elu(h) @ W1 + b1) -> sA (in place)
        accf a0 = {}, a1 = {};
        const _Float16* wr = wW1T + (size_t)wi * 16384 + wid * 4096;  // 4 fs x 8 cs x 512
        GEMM2(wr, sA, SH, 128, a0, a1)
        __syncthreads();   // all W1 reads of sA done
        #pragma unroll
        for (int nt = 0; nt < 2; ++nt) {
          accf& A = nt ? a1 : a0;
          const int mrow = nt * 32 + col;
          #pragma unroll
          for (int g = 0; g < 4; ++g) {
            const int f = f0 + 8 * g + q4;
            const float4 bv = *(const float4*)&bb1[wi * 128 + f];
            hpack pk;
            #pragma unroll
            for (int r = 0; r < 4; ++r) pk[r] = (_Float16)eluf(A[4 * g + r] + (&bv.x)[r]);
            *(hpack*)&sA[mrow * SH + f] = pk;
          }
        }
      }
      __syncthreads();   // elu(t1) visible
      {  // gate = sigmoid(emb@Wc + bc) [f16-packed]; t2 = elu(t1)@W2 + b2 ; h += t2*gate
        // gate GEMM first: its f32 accumulators retire into 8 VGPRs of f16
        // before the W2 accumulators go live (keeps peak unified regs <= 128).
        hpack gpk[2][4];
        {
          accf g0 = {}, g1 = {};
          const _Float16* wrc = wWcT + (size_t)wi * 8192 + wid * 2048;
          GEMM2(wrc, sE, SE, 64, g0, g1)
          #pragma unroll
          for (int nt = 0; nt < 2; ++nt) {
            accf& AG = nt ? g1 : g0;
            #pragma unroll
            for (int g = 0; g < 4; ++g) {
              const int f = f0 + 8 * g + q4;
              const float4 bcv = *(const float4*)&bbc[wi * 128 + f];
              #pragma unroll
              for (int r = 0; r < 4; ++r)
                gpk[nt][g][r] = (_Float16)sigmf(AG[4 * g + r] + (&bcv.x)[r]);
            }
          }
        }
        __builtin_amdgcn_sched_barrier(0);  // don't interleave W2 into gate (reg pressure)
        accf a0 = {}, a1 = {};
        const _Float16* wr2 = wW2T + (size_t)wi * 16384 + wid * 4096;
        GEMM2(wr2, sA, SH, 128, a0, a1)
        __syncthreads();   // all W2 reads of sA done
        const bool last = (jb == 1);
        #pragma unroll
        for (int nt = 0; nt < 2; ++nt) {
          accf& A2 = nt ? a1 : a0;
          accf& H  = nt ? h1 : h0;
          const int mrow = nt * 32 + col;
          #pragma unroll
          for (int g = 0; g < 4; ++g) {
            const int f = f0 + 8 * g + q4;
            const float4 b2v = *(const float4*)&bb2[wi * 128 + f];
            hpack pk;
            #pragma unroll
            for (int r = 0; r < 4; ++r) {
              const float hv = H[4 * g + r] + (A2[4 * g + r] + (&b2v.x)[r]) * (float)gpk[nt][g][r];
              H[4 * g + r] = hv;
              pk[r] = (_Float16)(last ? hv : eluf(hv));  // last block: stage RAW h
            }
            *(hpack*)&sA[mrow * SH + f] = pk;
          }
        }
      }
      __syncthreads();   // new act visible
    }

    // ---- p = h @ out_W + out_b  (waves 0-2; writes sP, no WAR barrier needed) ----
    if (wid < 3) {
      accf o0 = {}, o1 = {};
      const _Float16* wr = wOutT + (size_t)l * 12288 + wid * 4096;  // 3 fs x 8 cs x 512
      GEMM2(wr, sA, SH, 128, o0, o1)
      #pragma unroll
      for (int nt = 0; nt < 2; ++nt) {
        accf& A = nt ? o1 : o0;
        const int mrow = nt * 32 + col;
        #pragma unroll
        for (int g = 0; g < 4; ++g) {
          const int f = f0 + 8 * g + q4;
          const float4 ov = *(const float4*)&obias[l * 96 + f];
          hpack pk;
          #pragma unroll
          for (int r = 0; r < 4; ++r) pk[r] = (_Float16)(A[4 * g + r] + (&ov.x)[r]);
          *(hpack*)&sP[mrow * SP + f] = pk;
        }
      }
    }
    __syncthreads();   // (D) p visible in sP

    // ---- rational-quadratic spline: wave 0, one lane per sample ----
    // waves 1-3 fall through to next layer's ctx GEMM + epilogue (sE/sA only,
    // disjoint from sP) and wait for wave 0 at (B).
    if (tid < 64) {
      const float invS = 0.08838834764831845f;  // 1/sqrt(128)
      const _Float16* pmv = &sP[tid * SP];
      auto pm = [&](int i) -> float { return (float)pmv[i]; };
      float mw = pm(0), mh = pm(32);
      #pragma unroll
      for (int i = 1; i < 32; ++i) {
        mw = fmaxf(mw, pm(i));
        mh = fmaxf(mh, pm(32 + i));
      }
      float sw = 0.f, sh = 0.f;
      #pragma unroll
      for (int i = 0; i < 32; ++i) {
        sw += __expf((pm(i) - mw) * invS);
        sh += __expf((pm(32 + i) - mh) * invS);
      }
      const float cw_scale = (1.0f - cMB * 32.f) / sw;
      const float ch_scale = (1.0f - cMB * 32.f) / sh;
      const float yc = fminf(fmaxf(z, -cTB), cTB);

      int idx = 0;
      float cum = 0.f, cw_k = -cTB, cw_k1 = cTB;
      bool take = true;
      #pragma unroll
      for (int i = 1; i <= 32; ++i) {
        float cwi;
        if (i < 32) {
          cum += cMB + __expf((pm(i - 1) - mw) * invS) * cw_scale;
          cwi = 2.f * cTB * cum - cTB;
        } else {
          cwi = cTB;
        }
        if (take) { cw_k1 = cwi; take = false; }
        if (i < 32 && yc >= cwi) { idx = i; cw_k = cwi; take = true; }
      }

      cum = 0.f;
      float ch_k = -cTB, ch_k1 = cTB;
      #pragma unroll
      for (int i = 1; i < 32; ++i) {
        cum += cMB + __expf((pm(32 + i - 1) - mh) * invS) * ch_scale;
        const float chi = 2.f * cTB * cum - cTB;
        if (i == idx) ch_k = chi;
        if (i == idx + 1) ch_k1 = chi;
      }

      const float w_k = cw_k1 - cw_k;
      const float h_k = ch_k1 - ch_k;
      const float d_k  = (idx == 0)  ? 1.f : cMD + softplusf_(pm(64 + idx - 1));
      const float d_k1 = (idx == 31) ? 1.f : cMD + softplusf_(pm(64 + idx));

      const float s_k  = h_k / w_k;
      const float th   = (yc - cw_k) / w_k;
      const float th1m = th * (1.f - th);
      const float numv = h_k * (s_k * th * th + d_k * th1m);
      const float denv = s_k + (d_k + d_k1 - 2.f * s_k) * th1m;
      const float outv = ch_k + numv / denv;
      const float omt  = 1.f - th;
      const float dnum = s_k * s_k * (d_k1 * th * th + 2.f * s_k * th1m + d_k * omt * omt);
      const float ladv = __logf(dnum) - 2.f * __logf(denv);
      const bool inside = (z >= -cTB) && (z <= cTB);
      if (inside) { z = outv; lad += ladv; }
    }
  }

  if (tid < 64) {
    gout[m0 + tid] = -0.5f * z * z - 0.9189385332046727f + lad;
  }
}

extern "C" void kernel_launch(void* const* d_in, const int* in_sizes, int n_in,
                              void* d_out, int out_size, void* d_ws, size_t ws_size,
                              hipStream_t stream) {
  const float* gy   = (const float*)d_in[0];
  const float* gctx = (const float*)d_in[1];
  const float* eW1  = (const float*)d_in[2];
  const float* eb1  = (const float*)d_in[3];
  const float* eW2  = (const float*)d_in[4];
  const float* eb2  = (const float*)d_in[5];
  const float* eW3  = (const float*)d_in[6];
  const float* eb3  = (const float*)d_in[7];
  const float* gib  = (const float*)d_in[8];
  const float* gcW  = (const float*)d_in[9];
  const float* gcb  = (const float*)d_in[10];
  const float* bW1  = (const float*)d_in[11];
  const float* bb1  = (const float*)d_in[12];
  const float* bW2  = (const float*)d_in[13];
  const float* bb2  = (const float*)d_in[14];
  const float* bWc  = (const float*)d_in[15];
  const float* bbc  = (const float*)d_in[16];
  const float* goW  = (const float*)d_in[17];
  const float* gob  = (const float*)d_in[18];

  _Float16* ws    = (_Float16*)d_ws;
  _Float16* wE2T  = ws;                  // 64*64
  _Float16* wE3T  = wE2T + 4096;         // 64*64
  _Float16* wCtxT = wE3T + 4096;         // 6*128*64
  _Float16* wW1T  = wCtxT + 49152;       // 12*128*128
  _Float16* wW2T  = wW1T + 196608;       // 12*128*128
  _Float16* wWcT  = wW2T + 196608;       // 12*128*64
  _Float16* wOutT = wWcT + 98304;        // 6*96*128
  float*    cb    = (float*)(wOutT + 73728);  // 6*128 combined ctx bias
  float*    ob    = cb + 768;                 // 6*96 padded out bias

  auto prep = [&](const float* s, _Float16* d, int K, int F, int Fp, int n) {
    int tot = n * Fp * K;
    prep_frag<<<(tot + 255) / 256, 256, 0, stream>>>(s, d, K, F, Fp, tot);
  };
  prep(eW2, wE2T, 64, 64, 64, 1);
  prep(eW3, wE3T, 64, 64, 64, 1);
  prep(gcW, wCtxT, 64, 128, 128, 6);
  prep(bW1, wW1T, 128, 128, 128, 12);
  prep(bW2, wW2T, 128, 128, 128, 12);
  prep(bWc, wWcT, 64, 128, 128, 12);
  prep(goW, wOutT, 128, 95, 96, 6);
  prep_bias<<<3, 256, 0, stream>>>(gib, gcb, gob, cb, ob);

  nsf_mfma<<<dim3(262144 / 64), dim3(256), 0, stream>>>(
      gy, gctx, eW1, eb1, eb2, eb3, cb, bb1, bb2, bbc, ob,
      wE2T, wE3T, wCtxT, wW1T, wW2T, wWcT, wOutT, (float*)d_out);
}

// Round 13
// 830.297 us; speedup vs baseline: 1.0190x; 1.0190x over previous
//
#include <hip/hip_runtime.h>
#include <math.h>

typedef _Float16 hfrag  __attribute__((ext_vector_type(8)));  // 8 f16 = 4 VGPR (MFMA A/B)
typedef _Float16 hpack  __attribute__((ext_vector_type(4)));  // 4 f16 = 8B packed store
typedef float    accf   __attribute__((ext_vector_type(16))); // MFMA C/D

constexpr float cTB = 6.0f;
constexpr float cMB = 0.001f;
constexpr float cMD = 0.001f;

constexpr int SH = 136;   // act buffer stride (halves)
constexpr int SE = 72;    // emb buffer stride (halves)
constexpr int SP = 100;   // dedicated p buffer stride (halves)

__device__ __forceinline__ float eluf(float x)  { return x > 0.f ? x : __expf(x) - 1.f; }
__device__ __forceinline__ float sigmf(float x) { return 1.f / (1.f + __expf(-x)); }
__device__ __forceinline__ float softplusf_(float x) { return x > 20.f ? x : log1pf(__expf(x)); }

// ---------------- weight prep: fp32 [n][K][F] -> fragment-ordered f16 ----------------
// dst layout [n][fs][cstep][lane][8]: lane l of fragment (fs,cstep) holds
//   W[k = cstep*16 + (l>>5)*8 + j][f = fs*32 + (l&31)],  j = 0..7
__global__ void prep_frag(const float* __restrict__ src, _Float16* __restrict__ dst,
                          int K, int F, int Fpad, int total) {
  int idx = blockIdx.x * 256 + threadIdx.x;
  if (idx >= total) return;
  const int j    = idx & 7;
  const int lane = (idx >> 3) & 63;
  const int rest = idx >> 9;              // [n][fs][cstep]
  const int csteps = K >> 4;
  const int cstep  = rest % csteps;
  const int rest2  = rest / csteps;
  const int fslices = Fpad >> 5;
  const int fs = rest2 % fslices;
  const int n  = rest2 / fslices;
  const int f  = fs * 32 + (lane & 31);
  const int k  = cstep * 16 + ((lane >> 5) << 3) + j;
  float v = (f < F) ? src[((size_t)n * K + k) * F + f] : 0.f;
  dst[idx] = (_Float16)v;
}

// ---------------- bias prep: cbias = init_b + ctx_b; obias = out_b padded to 96 ----
__global__ void prep_bias(const float* __restrict__ gib, const float* __restrict__ gcb,
                          const float* __restrict__ gob, float* __restrict__ cb,
                          float* __restrict__ ob) {
  int i = blockIdx.x * 256 + threadIdx.x;
  if (i < 768) cb[i] = gib[i] + gcb[i];            // 6 layers x 128
  if (i < 576) {                                   // 6 layers x 96 (pad col 95)
    int l = i / 96, f = i % 96;
    ob[i] = (f < 95) ? gob[l * 95 + f] : 0.f;
  }
}

// GEMM, B from LDS: D[f][m] += W^T[f][k] * Act^T[k][m].  A-frag contiguous burst,
// B-frag col = m (LDS [m][k]).  Two n-tiles (m 0-31, 32-63).
// K-loop chunked at 4 c-steps (sched_barrier between): R11-verified optimum —
// caps fragment hoisting at ~48 regs (spill 63->33 MB); chunk-2 (R12) regressed.
#define GEMM2(WBASE, BPTR, BSTRIDE, KDIM, A0, A1)                              \
  _Pragma("unroll")                                                            \
  for (int cc = 0; cc < (KDIM); cc += 64) {                                    \
    _Pragma("unroll")                                                          \
    for (int c = cc; c < cc + 64; c += 16) {                                   \
      hfrag av = *(const hfrag*)((WBASE) + (c << 5) + lane8);                  \
      hfrag b0 = *(const hfrag*)((BPTR) + col * (BSTRIDE) + c + q8);           \
      hfrag b1 = *(const hfrag*)((BPTR) + (32 + col) * (BSTRIDE) + c + q8);    \
      A0 = __builtin_amdgcn_mfma_f32_32x32x16_f16(av, b0, A0, 0, 0, 0);        \
      A1 = __builtin_amdgcn_mfma_f32_32x32x16_f16(av, b1, A1, 0, 0, 0);        \
    }                                                                          \
    __builtin_amdgcn_sched_barrier(0);                                         \
  }

__global__ __launch_bounds__(256, 4) void nsf_mfma(
    const float* __restrict__ gy,   const float* __restrict__ gctx,
    const float* __restrict__ eW1,  const float* __restrict__ eb1,
    const float* __restrict__ eb2,  const float* __restrict__ eb3,
    const float* __restrict__ cbias, const float* __restrict__ bb1,
    const float* __restrict__ bb2,  const float* __restrict__ bbc,
    const float* __restrict__ obias,
    const _Float16* __restrict__ wE2T, const _Float16* __restrict__ wE3T,
    const _Float16* __restrict__ wCtxT, const _Float16* __restrict__ wW1T,
    const _Float16* __restrict__ wW2T,  const _Float16* __restrict__ wWcT,
    const _Float16* __restrict__ wOutT, float* __restrict__ gout)
{
  __shared__ _Float16 sA[64 * SH];   // single in-place act buffer
  __shared__ _Float16 sE[64 * SE];   // embedding [m][k]
  __shared__ _Float16 sP[64 * SP];   // dedicated p buffer (spline input)

  const int tid  = threadIdx.x;
  const int wid  = tid >> 6;      // wave 0..3 -> f-slice
  const int lane = tid & 63;
  const int col  = lane & 31;     // MFMA col (= m_local)
  const int q    = lane >> 5;     // k-half selector
  const int q8   = q * 8;
  const int q4   = q * 4;
  const int f0   = wid * 32;
  const int m0   = blockIdx.x * 64;
  const int lane8 = lane * 8;     // fragment-ordered weight lane offset (halves)

  // ---------------- embedding ----------------
  {  // stage 1: fp32, 4 e-groups x 64 m -> sE
    const int m  = tid & 63;
    const int eg = tid >> 6;
    const float2 c2 = *(const float2*)&gctx[(size_t)(m0 + m) * 2];
    #pragma unroll
    for (int j = 0; j < 16; ++j) {
      const int e = eg * 16 + j;
      sE[m * SE + e] = (_Float16)eluf(c2.x * eW1[e] + c2.y * eW1[64 + e] + eb1[e]);
    }
  }
  __syncthreads();
  {  // stage 2: MFMA, each wave one (ft, nt) tile: sE -> sA (stride SE)
    const int ft = wid & 1, nt = wid >> 1;
    accf a = {};
    const _Float16* wr = wE2T + ft * 2048;     // [fs][cs=4][64][8]
    #pragma unroll
    for (int c = 0; c < 64; c += 16) {
      hfrag av = *(const hfrag*)(wr + (c << 5) + lane8);
      hfrag bv = *(const hfrag*)(&sE[(nt * 32 + col) * SE + c + q8]);
      a = __builtin_amdgcn_mfma_f32_32x32x16_f16(av, bv, a, 0, 0, 0);
    }
    const int mrow = nt * 32 + col;
    __syncthreads();   // sE reads done everywhere before stage-3 overwrites
    #pragma unroll
    for (int g = 0; g < 4; ++g) {
      const int e = 32 * ft + 8 * g + q4;
      const float4 b = *(const float4*)&eb2[e];
      hpack pk;
      #pragma unroll
      for (int r = 0; r < 4; ++r) pk[r] = (_Float16)eluf(a[4 * g + r] + (&b.x)[r]);
      *(hpack*)&sA[mrow * SE + e] = pk;
    }
  }
  __syncthreads();
  {  // stage 3: MFMA: sA -> sE (final embedding)
    const int ft = wid & 1, nt = wid >> 1;
    accf a = {};
    const _Float16* wr = wE3T + ft * 2048;
    #pragma unroll
    for (int c = 0; c < 64; c += 16) {
      hfrag av = *(const hfrag*)(wr + (c << 5) + lane8);
      hfrag bv = *(const hfrag*)(&sA[(nt * 32 + col) * SE + c + q8]);
      a = __builtin_amdgcn_mfma_f32_32x32x16_f16(av, bv, a, 0, 0, 0);
    }
    const int mrow = nt * 32 + col;
    #pragma unroll
    for (int g = 0; g < 4; ++g) {
      const int e = 32 * ft + 8 * g + q4;
      const float4 b = *(const float4*)&eb3[e];
      hpack pk;
      #pragma unroll
      for (int r = 0; r < 4; ++r) pk[r] = (_Float16)eluf(a[4 * g + r] + (&b.x)[r]);
      *(hpack*)&sE[mrow * SE + e] = pk;
    }
  }
  __syncthreads();

  // ---------------- flow layers ----------------
  float z = 0.f, lad = 0.f;
  if (tid < 64) z = gy[m0 + tid];

  accf h0, h1;   // raw h (fp32) for this wave's f-slice, n-tiles 0/1

  #pragma unroll 1
  for (int l = 0; l < 6; ++l) {
    // ---- ctx GEMM (reads sE only): waves 1-3 run ahead here while wave 0
    //      finishes the previous layer's spline (reads sP — disjoint buffer).
    {
      accf a0 = {}, a1 = {};
      const _Float16* wr = wCtxT + (size_t)l * 8192 + wid * 2048;  // 4 fs x 4 cs x 512
      GEMM2(wr, sE, SE, 64, a0, a1)
      // ---- ctx epilogue: h = acc + (init_b+ctx_b); write elu(h) -> sA ----
      #pragma unroll
      for (int nt = 0; nt < 2; ++nt) {
        accf& A = nt ? a1 : a0;
        accf& H = nt ? h1 : h0;
        const int mrow = nt * 32 + col;
        #pragma unroll
        for (int g = 0; g < 4; ++g) {
          const int f = f0 + 8 * g + q4;
          const float4 bi = *(const float4*)&cbias[l * 128 + f];
          hpack pk;
          #pragma unroll
          for (int r = 0; r < 4; ++r) {
            float hv = A[4 * g + r] + (&bi.x)[r];
            H[4 * g + r] = hv;
            pk[r] = (_Float16)eluf(hv);
          }
          *(hpack*)&sA[mrow * SH + f] = pk;
        }
      }
    }
    __syncthreads();   // (B) elu(h) visible

    // ---- residual blocks (in-place on sA) ----
    #pragma unroll 1
    for (int jb = 0; jb < 2; ++jb) {
      const int wi = l * 2 + jb;
      {  // t1 = elu(elu(h) @ W1 + b1) -> sA (in place)
        accf a0 = {}, a1 = {};
        const _Float16* wr = wW1T + (size_t)wi * 16384 + wid * 4096;  // 4 fs x 8 cs x 512
        GEMM2(wr, sA, SH, 128, a0, a1)
        __syncthreads();   // all W1 reads of sA done
        #pragma unroll
        for (int nt = 0; nt < 2; ++nt) {
          accf& A = nt ? a1 : a0;
          const int mrow = nt * 32 + col;
          #pragma unroll
          for (int g = 0; g < 4; ++g) {
            const int f = f0 + 8 * g + q4;
            const float4 bv = *(const float4*)&bb1[wi * 128 + f];
            hpack pk;
            #pragma unroll
            for (int r = 0; r < 4; ++r) pk[r] = (_Float16)eluf(A[4 * g + r] + (&bv.x)[r]);
            *(hpack*)&sA[mrow * SH + f] = pk;
          }
        }
      }
      __syncthreads();   // elu(t1) visible
      {  // gate = sigmoid(emb@Wc + bc) [f16-packed]; t2 = elu(t1)@W2 + b2 ; h += t2*gate
        // gate GEMM first: its f32 accumulators retire into 8 VGPRs of f16
        // before the W2 accumulators go live (keeps peak unified regs <= 128).
        hpack gpk[2][4];
        {
          accf g0 = {}, g1 = {};
          const _Float16* wrc = wWcT + (size_t)wi * 8192 + wid * 2048;
          GEMM2(wrc, sE, SE, 64, g0, g1)
          #pragma unroll
          for (int nt = 0; nt < 2; ++nt) {
            accf& AG = nt ? g1 : g0;
            #pragma unroll
            for (int g = 0; g < 4; ++g) {
              const int f = f0 + 8 * g + q4;
              const float4 bcv = *(const float4*)&bbc[wi * 128 + f];
              #pragma unroll
              for (int r = 0; r < 4; ++r)
                gpk[nt][g][r] = (_Float16)sigmf(AG[4 * g + r] + (&bcv.x)[r]);
            }
          }
        }
        __builtin_amdgcn_sched_barrier(0);  // don't interleave W2 into gate (reg pressure)
        accf a0 = {}, a1 = {};
        const _Float16* wr2 = wW2T + (size_t)wi * 16384 + wid * 4096;
        GEMM2(wr2, sA, SH, 128, a0, a1)
        __syncthreads();   // all W2 reads of sA done
        const bool last = (jb == 1);
        #pragma unroll
        for (int nt = 0; nt < 2; ++nt) {
          accf& A2 = nt ? a1 : a0;
          accf& H  = nt ? h1 : h0;
          const int mrow = nt * 32 + col;
          #pragma unroll
          for (int g = 0; g < 4; ++g) {
            const int f = f0 + 8 * g + q4;
            const float4 b2v = *(const float4*)&bb2[wi * 128 + f];
            hpack pk;
            #pragma unroll
            for (int r = 0; r < 4; ++r) {
              const float hv = H[4 * g + r] + (A2[4 * g + r] + (&b2v.x)[r]) * (float)gpk[nt][g][r];
              H[4 * g + r] = hv;
              pk[r] = (_Float16)(last ? hv : eluf(hv));  // last block: stage RAW h
            }
            *(hpack*)&sA[mrow * SH + f] = pk;
          }
        }
      }
      __syncthreads();   // new act visible
    }

    // ---- p = h @ out_W + out_b  (waves 0-2; writes sP, no WAR barrier needed) ----
    if (wid < 3) {
      accf o0 = {}, o1 = {};
      const _Float16* wr = wOutT + (size_t)l * 12288 + wid * 4096;  // 3 fs x 8 cs x 512
      GEMM2(wr, sA, SH, 128, o0, o1)
      #pragma unroll
      for (int nt = 0; nt < 2; ++nt) {
        accf& A = nt ? o1 : o0;
        const int mrow = nt * 32 + col;
        #pragma unroll
        for (int g = 0; g < 4; ++g) {
          const int f = f0 + 8 * g + q4;
          const float4 ov = *(const float4*)&obias[l * 96 + f];
          hpack pk;
          #pragma unroll
          for (int r = 0; r < 4; ++r) pk[r] = (_Float16)(A[4 * g + r] + (&ov.x)[r]);
          *(hpack*)&sP[mrow * SP + f] = pk;
        }
      }
    }
    __syncthreads();   // (D) p visible in sP

    // ---- rational-quadratic spline: wave 0, one lane per sample ----
    // waves 1-3 fall through to next layer's ctx GEMM + epilogue (sE/sA only,
    // disjoint from sP) and wait for wave 0 at (B).
    // Strength-reduced: exps computed ONCE (bitwise-identical reuse in the
    // cumsum passes), max/sum as 4-way interleaved chains (dep depth 31 -> 10).
    if (tid < 64) {
      const float invS = 0.08838834764831845f;  // 1/sqrt(128)
      const _Float16* pmv = &sP[tid * SP];
      auto pm = [&](int i) -> float { return (float)pmv[i]; };

      float pw[32], ph[32];
      #pragma unroll
      for (int i = 0; i < 32; ++i) { pw[i] = pm(i); ph[i] = pm(32 + i); }

      // 4-way interleaved max
      float w0 = pw[0], w1 = pw[1], w2 = pw[2], w3 = pw[3];
      float h0m = ph[0], h1m = ph[1], h2m = ph[2], h3m = ph[3];
      #pragma unroll
      for (int i = 1; i < 8; ++i) {
        w0 = fmaxf(w0, pw[4 * i]);     w1 = fmaxf(w1, pw[4 * i + 1]);
        w2 = fmaxf(w2, pw[4 * i + 2]); w3 = fmaxf(w3, pw[4 * i + 3]);
        h0m = fmaxf(h0m, ph[4 * i]);     h1m = fmaxf(h1m, ph[4 * i + 1]);
        h2m = fmaxf(h2m, ph[4 * i + 2]); h3m = fmaxf(h3m, ph[4 * i + 3]);
      }
      const float mw = fmaxf(fmaxf(w0, w1), fmaxf(w2, w3));
      const float mh = fmaxf(fmaxf(h0m, h1m), fmaxf(h2m, h3m));

      // exps once, cached in registers
      float ew[32], eh[32];
      #pragma unroll
      for (int i = 0; i < 32; ++i) {
        ew[i] = __expf((pw[i] - mw) * invS);
        eh[i] = __expf((ph[i] - mh) * invS);
      }

      // 4-way interleaved sums
      float a0s = ew[0], a1s = ew[1], a2s = ew[2], a3s = ew[3];
      float b0s = eh[0], b1s = eh[1], b2s = eh[2], b3s = eh[3];
      #pragma unroll
      for (int i = 1; i < 8; ++i) {
        a0s += ew[4 * i];     a1s += ew[4 * i + 1];
        a2s += ew[4 * i + 2]; a3s += ew[4 * i + 3];
        b0s += eh[4 * i];     b1s += eh[4 * i + 1];
        b2s += eh[4 * i + 2]; b3s += eh[4 * i + 3];
      }
      const float sw = (a0s + a1s) + (a2s + a3s);
      const float sh = (b0s + b1s) + (b2s + b3s);

      const float cw_scale = (1.0f - cMB * 32.f) / sw;
      const float ch_scale = (1.0f - cMB * 32.f) / sh;
      const float yc = fminf(fmaxf(z, -cTB), cTB);

      int idx = 0;
      float cum = 0.f, cw_k = -cTB, cw_k1 = cTB;
      bool take = true;
      #pragma unroll
      for (int i = 1; i <= 32; ++i) {
        float cwi;
        if (i < 32) {
          cum += cMB + ew[i - 1] * cw_scale;
          cwi = 2.f * cTB * cum - cTB;
        } else {
          cwi = cTB;
        }
        if (take) { cw_k1 = cwi; take = false; }
        if (i < 32 && yc >= cwi) { idx = i; cw_k = cwi; take = true; }
      }

      cum = 0.f;
      float ch_k = -cTB, ch_k1 = cTB;
      #pragma unroll
      for (int i = 1; i < 32; ++i) {
        cum += cMB + eh[i - 1] * ch_scale;
        const float chi = 2.f * cTB * cum - cTB;
        if (i == idx) ch_k = chi;
        if (i == idx + 1) ch_k1 = chi;
      }

      const float w_k = cw_k1 - cw_k;
      const float h_k = ch_k1 - ch_k;
      const float d_k  = (idx == 0)  ? 1.f : cMD + softplusf_(pm(64 + idx - 1));
      const float d_k1 = (idx == 31) ? 1.f : cMD + softplusf_(pm(64 + idx));

      const float s_k  = h_k / w_k;
      const float th   = (yc - cw_k) / w_k;
      const float th1m = th * (1.f - th);
      const float numv = h_k * (s_k * th * th + d_k * th1m);
      const float denv = s_k + (d_k + d_k1 - 2.f * s_k) * th1m;
      const float outv = ch_k + numv / denv;
      const float omt  = 1.f - th;
      const float dnum = s_k * s_k * (d_k1 * th * th + 2.f * s_k * th1m + d_k * omt * omt);
      const float ladv = __logf(dnum) - 2.f * __logf(denv);
      const bool inside = (z >= -cTB) && (z <= cTB);
      if (inside) { z = outv; lad += ladv; }
    }
  }

  if (tid < 64) {
    gout[m0 + tid] = -0.5f * z * z - 0.9189385332046727f + lad;
  }
}

extern "C" void kernel_launch(void* const* d_in, const int* in_sizes, int n_in,
                              void* d_out, int out_size, void* d_ws, size_t ws_size,
                              hipStream_t stream) {
  const float* gy   = (const float*)d_in[0];
  const float* gctx = (const float*)d_in[1];
  const float* eW1  = (const float*)d_in[2];
  const float* eb1  = (const float*)d_in[3];
  const float* eW2  = (const float*)d_in[4];
  const float* eb2  = (const float*)d_in[5];
  const float* eW3  = (const float*)d_in[6];
  const float* eb3  = (const float*)d_in[7];
  const float* gib  = (const float*)d_in[8];
  const float* gcW  = (const float*)d_in[9];
  const float* gcb  = (const float*)d_in[10];
  const float* bW1  = (const float*)d_in[11];
  const float* bb1  = (const float*)d_in[12];
  const float* bW2  = (const float*)d_in[13];
  const float* bb2  = (const float*)d_in[14];
  const float* bWc  = (const float*)d_in[15];
  const float* bbc  = (const float*)d_in[16];
  const float* goW  = (const float*)d_in[17];
  const float* gob  = (const float*)d_in[18];

  _Float16* ws    = (_Float16*)d_ws;
  _Float16* wE2T  = ws;                  // 64*64
  _Float16* wE3T  = wE2T + 4096;         // 64*64
  _Float16* wCtxT = wE3T + 4096;         // 6*128*64
  _Float16* wW1T  = wCtxT + 49152;       // 12*128*128
  _Float16* wW2T  = wW1T + 196608;       // 12*128*128
  _Float16* wWcT  = wW2T + 196608;       // 12*128*64
  _Float16* wOutT = wWcT + 98304;        // 6*96*128
  float*    cb    = (float*)(wOutT + 73728);  // 6*128 combined ctx bias
  float*    ob    = cb + 768;                 // 6*96 padded out bias

  auto prep = [&](const float* s, _Float16* d, int K, int F, int Fp, int n) {
    int tot = n * Fp * K;
    prep_frag<<<(tot + 255) / 256, 256, 0, stream>>>(s, d, K, F, Fp, tot);
  };
  prep(eW2, wE2T, 64, 64, 64, 1);
  prep(eW3, wE3T, 64, 64, 64, 1);
  prep(gcW, wCtxT, 64, 128, 128, 6);
  prep(bW1, wW1T, 128, 128, 128, 12);
  prep(bW2, wW2T, 128, 128, 128, 12);
  prep(bWc, wWcT, 64, 128, 128, 12);
  prep(goW, wOutT, 128, 95, 96, 6);
  prep_bias<<<3, 256, 0, stream>>>(gib, gcb, gob, cb, ob);

  nsf_mfma<<<dim3(262144 / 64), dim3(256), 0, stream>>>(
      gy, gctx, eW1, eb1, eb2, eb3, cb, bb1, bb2, bbc, ob,
      wE2T, wE3T, wCtxT, wW1T, wW2T, wWcT, wOutT, (float*)d_out);
}